// Round 3
// baseline (572.539 us; speedup 1.0000x reference)
//
#include <hip/hip_runtime.h>
#include <math.h>

#define H  1024
#define H2 2048
#define V  50257
#define L  512
#define NBL ((V + 15) / 16)   // 3142 blocks for logits (16 rows/block)

__device__ __forceinline__ float dot4(float4 a, float4 b) {
    return a.x*b.x + a.y*b.y + a.z*b.z + a.w*b.w;
}
__device__ __forceinline__ float wave_red_sum(float acc) {
    for (int off = 32; off > 0; off >>= 1) acc += __shfl_down(acc, off, 64);
    return acc;
}

// ---- K1: blocks 0..127 attention scores (wave/score); 128..895 gh GEMV -----
// scores[l] = dot(h0, enc[l]);  gh[r] = dot(h0, w_hh[r]) + b_hh[r]
__global__ void __launch_bounds__(256) k_pre(
        const float* __restrict__ h0, const float* __restrict__ enc,
        const float* __restrict__ w_hh, const float* __restrict__ b_hh,
        float* __restrict__ scores, float* __restrict__ gh,
        int* __restrict__ counter) {
    int t = threadIdx.x, lane = t & 63, wv = t >> 6;
    if (blockIdx.x == 0 && t == 0) counter[0] = 0;   // for k_logits_lse
    const float4* h4 = (const float4*)h0;
    if (blockIdx.x < 128) {
        int l = blockIdx.x * 4 + wv;                 // 0..511
        const float4* e4 = (const float4*)(enc + (size_t)l * H);
        float acc = 0.f;
        #pragma unroll
        for (int j = 0; j < 4; ++j) acc += dot4(e4[j * 64 + lane], h4[j * 64 + lane]);
        acc = wave_red_sum(acc);
        if (lane == 0) scores[l] = acc;
    } else {
        int row = (blockIdx.x - 128) * 4 + wv;       // 0..3071
        const float4* wr = (const float4*)(w_hh + (size_t)row * H);
        float acc = 0.f;
        #pragma unroll
        for (int j = 0; j < 4; ++j) acc += dot4(wr[j * 64 + lane], h4[j * 64 + lane]);
        acc = wave_red_sum(acc);
        if (lane == 0) gh[row] = acc + b_hh[row];
    }
}

// ---- K2: softmax over 512 scores (redundant per block) + attn_applied ------
__global__ void __launch_bounds__(256) k_softmax_attn(
        const float* __restrict__ enc, const float* __restrict__ scores,
        float* __restrict__ attn_applied, float* __restrict__ d_out) {
    __shared__ float wl[L];
    __shared__ float red[256];
    __shared__ float part[8][32];
    int t = threadIdx.x;
    float s0 = scores[t], s1 = scores[t + 256];
    red[t] = fmaxf(s0, s1);
    __syncthreads();
    for (int off = 128; off > 0; off >>= 1) {
        if (t < off) red[t] = fmaxf(red[t], red[t + off]);
        __syncthreads();
    }
    float gmax = red[0];
    __syncthreads();
    float e0 = expf(s0 - gmax), e1 = expf(s1 - gmax);
    red[t] = e0 + e1;
    __syncthreads();
    for (int off = 128; off > 0; off >>= 1) {
        if (t < off) red[t] += red[t + off];
        __syncthreads();
    }
    float inv = 1.0f / red[0];
    wl[t]       = e0 * inv;
    wl[t + 256] = e1 * inv;
    __syncthreads();
    if (blockIdx.x == 0) {
        d_out[V + H + t]       = wl[t];
        d_out[V + H + t + 256] = wl[t + 256];
    }
    int c = t & 31, sIdx = t >> 5;
    int col = blockIdx.x * 32 + c;
    float acc = 0.f;
    for (int l = sIdx * 64; l < sIdx * 64 + 64; ++l)
        acc += wl[l] * enc[(size_t)l * H + col];
    part[sIdx][c] = acc;
    __syncthreads();
    if (sIdx == 0) {
        float sum = 0.f;
        #pragma unroll
        for (int k = 0; k < 8; ++k) sum += part[k][c];
        attn_applied[col] = sum;
    }
}

// ---- K3: x = relu([embedded, attn_applied] @ Wc^T + bc) --------------------
__global__ void __launch_bounds__(256) k_combine(
        const float* __restrict__ emb_w, const int* __restrict__ tok,
        const float* __restrict__ attn_applied, const float* __restrict__ Wc,
        const float* __restrict__ bc, float* __restrict__ x) {
    __shared__ float comb[H2];
    int t = threadIdx.x;
    int tk = tok[0];
    ((float4*)comb)[t]       = ((const float4*)(emb_w + (size_t)tk * H))[t];
    ((float4*)comb)[t + 256] = ((const float4*)attn_applied)[t];
    __syncthreads();
    int lane = t & 63, wv = t >> 6;
    int row = blockIdx.x * 4 + wv;
    const float4* wr = (const float4*)(Wc + (size_t)row * H2);
    float acc = 0.f;
    #pragma unroll
    for (int j = 0; j < 8; ++j) acc += dot4(wr[j * 64 + lane], ((const float4*)comb)[j * 64 + lane]);
    acc = wave_red_sum(acc);
    if (lane == 0) x[row] = fmaxf(acc + bc[row], 0.f);
}

// ---- K4: gi rows (r,z,n per unit) + GRU elementwise, fused -----------------
__global__ void __launch_bounds__(256) k_gi_gru(
        const float* __restrict__ x, const float* __restrict__ h0,
        const float* __restrict__ w_ih, const float* __restrict__ b_ih,
        const float* __restrict__ gh, float* __restrict__ d_out,
        float* __restrict__ hnew) {
    int t = threadIdx.x, lane = t & 63, wv = t >> 6;
    int i = blockIdx.x * 4 + wv;                        // 0..1023
    const float4* xv = (const float4*)x;
    float g[3];
    #pragma unroll
    for (int k = 0; k < 3; ++k) {
        const float4* wr = (const float4*)(w_ih + (size_t)(k * H + i) * H);
        float acc = 0.f;
        #pragma unroll
        for (int j = 0; j < 4; ++j) acc += dot4(wr[j * 64 + lane], xv[j * 64 + lane]);
        g[k] = wave_red_sum(acc);
    }
    if (lane == 0) {
        float gir = g[0] + b_ih[i];
        float giz = g[1] + b_ih[H + i];
        float gin = g[2] + b_ih[2 * H + i];
        float r = 1.f / (1.f + expf(-(gir + gh[i])));
        float z = 1.f / (1.f + expf(-(giz + gh[H + i])));
        float n = tanhf(gin + r * gh[2 * H + i]);
        float h = (1.f - z) * n + z * h0[i];
        d_out[V + i] = h;
        hnew[i] = h;
    }
}

// ---- K5: logits (4 rows/wave) + per-block LSE partial + last-block final ---
__global__ void __launch_bounds__(256) k_logits_lse(
        const float* __restrict__ hnew, const float* __restrict__ out_w,
        const float* __restrict__ out_b, float* __restrict__ logits,
        float* __restrict__ pm, float* __restrict__ ps,
        int* __restrict__ counter, float* __restrict__ fin) {
    __shared__ float hs[H];
    __shared__ float blk[16];
    __shared__ float red[4];
    __shared__ int last;
    int t = threadIdx.x, lane = t & 63, wv = t >> 6;
    ((float4*)hs)[t] = ((const float4*)hnew)[t];
    __syncthreads();
    const float4* hs4 = (const float4*)hs;
    int row0 = (blockIdx.x * 4 + wv) * 4;
    int r0 = row0     < V ? row0     : V - 1;
    int r1 = row0 + 1 < V ? row0 + 1 : V - 1;
    int r2 = row0 + 2 < V ? row0 + 2 : V - 1;
    int r3 = row0 + 3 < V ? row0 + 3 : V - 1;
    const float4* w0 = (const float4*)(out_w + (size_t)r0 * H);
    const float4* w1 = (const float4*)(out_w + (size_t)r1 * H);
    const float4* w2 = (const float4*)(out_w + (size_t)r2 * H);
    const float4* w3 = (const float4*)(out_w + (size_t)r3 * H);
    float a0 = 0.f, a1 = 0.f, a2 = 0.f, a3 = 0.f;
    #pragma unroll
    for (int j = 0; j < 4; ++j) {
        float4 b = hs4[j * 64 + lane];
        a0 += dot4(w0[j * 64 + lane], b);
        a1 += dot4(w1[j * 64 + lane], b);
        a2 += dot4(w2[j * 64 + lane], b);
        a3 += dot4(w3[j * 64 + lane], b);
    }
    for (int off = 32; off > 0; off >>= 1) {
        a0 += __shfl_down(a0, off, 64);
        a1 += __shfl_down(a1, off, 64);
        a2 += __shfl_down(a2, off, 64);
        a3 += __shfl_down(a3, off, 64);
    }
    if (lane == 0) {
        float v0 = a0 + out_b[r0], v1 = a1 + out_b[r1];
        float v2 = a2 + out_b[r2], v3 = a3 + out_b[r3];
        if (row0     < V) logits[row0]     = v0; else v0 = -INFINITY;
        if (row0 + 1 < V) logits[row0 + 1] = v1; else v1 = -INFINITY;
        if (row0 + 2 < V) logits[row0 + 2] = v2; else v2 = -INFINITY;
        if (row0 + 3 < V) logits[row0 + 3] = v3; else v3 = -INFINITY;
        blk[wv * 4 + 0] = v0; blk[wv * 4 + 1] = v1;
        blk[wv * 4 + 2] = v2; blk[wv * 4 + 3] = v3;
    }
    __syncthreads();
    if (t == 0) {
        float m = blk[0];
        #pragma unroll
        for (int k = 1; k < 16; ++k) m = fmaxf(m, blk[k]);
        float s = 0.f;
        #pragma unroll
        for (int k = 0; k < 16; ++k) s += expf(blk[k] - m);
        pm[blockIdx.x] = m;
        ps[blockIdx.x] = s;
        __threadfence();
        int old = atomicAdd(counter, 1);
        last = (old == (int)gridDim.x - 1) ? 1 : 0;
    }
    __syncthreads();
    if (last) {
        __threadfence();
        // pass 1: global max
        float m = -INFINITY;
        for (int i = t; i < NBL; i += 256) m = fmaxf(m, pm[i]);
        for (int off = 32; off > 0; off >>= 1) m = fmaxf(m, __shfl_down(m, off, 64));
        if (lane == 0) red[wv] = m;
        __syncthreads();
        float M = fmaxf(fmaxf(red[0], red[1]), fmaxf(red[2], red[3]));
        __syncthreads();
        // pass 2: rescaled sum
        float s = 0.f;
        for (int i = t; i < NBL; i += 256) s += ps[i] * expf(pm[i] - M);
        s = wave_red_sum(s);
        if (lane == 0) red[wv] = s;
        __syncthreads();
        if (t == 0) {
            fin[0] = M;
            fin[1] = logf(red[0] + red[1] + red[2] + red[3]);
        }
    }
}

// ---- K6: logp = logits - M - logΣ, in place --------------------------------
__global__ void __launch_bounds__(256) k_logp(
        float* __restrict__ d_out, const float* __restrict__ fin) {
    int i = blockIdx.x * 256 + threadIdx.x;
    float c = fin[0] + fin[1];
    if (i < V) d_out[i] = d_out[i] - c;
}

extern "C" void kernel_launch(void* const* d_in, const int* in_sizes, int n_in,
                              void* d_out, int out_size, void* d_ws, size_t ws_size,
                              hipStream_t stream) {
    const int*   tok    = (const int*)d_in[0];
    const float* hidden = (const float*)d_in[1];
    const float* enc    = (const float*)d_in[2];
    const float* emb_w  = (const float*)d_in[3];
    const float* Wc     = (const float*)d_in[4];
    const float* bc     = (const float*)d_in[5];
    const float* w_ih   = (const float*)d_in[6];
    const float* w_hh   = (const float*)d_in[7];
    const float* b_ih   = (const float*)d_in[8];
    const float* b_hh   = (const float*)d_in[9];
    const float* out_w  = (const float*)d_in[10];
    const float* out_b  = (const float*)d_in[11];
    float* out = (float*)d_out;
    float* ws  = (float*)d_ws;

    float* scores       = ws;            // 512
    float* gh           = ws + 1024;     // 3072
    float* attn_applied = ws + 4096;     // 1024
    float* xbuf         = ws + 5120;     // 1024
    float* hnew         = ws + 6144;     // 1024
    float* pm           = ws + 7168;     // 3142
    float* psum         = ws + 10368;    // 3142
    int*   counter      = (int*)(ws + 13568);
    float* fin          = ws + 13572;    // 2

    k_pre         <<<896, 256, 0, stream>>>(hidden, enc, w_hh, b_hh, scores, gh, counter);
    k_softmax_attn<<<32,  256, 0, stream>>>(enc, scores, attn_applied, out);
    k_combine     <<<256, 256, 0, stream>>>(emb_w, tok, attn_applied, Wc, bc, xbuf);
    k_gi_gru      <<<256, 256, 0, stream>>>(xbuf, hidden, w_ih, b_ih, gh, out, hnew);
    k_logits_lse  <<<NBL, 256, 0, stream>>>(hnew, out_w, out_b, out, pm, psum, counter, fin);
    k_logp        <<<(V + 255) / 256, 256, 0, stream>>>(out, fin);
}